// Round 2
// baseline (503.853 us; speedup 1.0000x reference)
//
#include <hip/hip_runtime.h>
#include <hip/hip_bf16.h>
#include <math.h>

// Dual-attention block, bf16 MFMA. R11 = R10 plus GEMM restructures:
//  - gemm_ep: 256x256 tile, 512 thr (8 waves 2Mx4N), 128KB dbuf LDS,
//    depth-2 pipeline with counted s_waitcnt vmcnt(8) (never 0 in main loop),
//    raw s_barrier, setprio(1) around MFMA clusters, bF cached in regs.
//  - gemm_o: BM 64->128 (grid 256 blocks), per-wave 64x64, MFMA:ds_read 2.0
//    (was 0.9), old proven 2-barrier schedule.
// ws layout (bytes from d_ws; ws is 1GB):
//   0..4MB    bf16 weights  | 4..12 normed | 12..20 qb | 20..28 kb | 28..36 vb
//   36..44    ctx | 44..60 h2 (fp32) | 60..60.03 rmsbuf | 61..69 h2b
//   70..72    rope table (float2[8192][32])

typedef __bf16 bf16x8 __attribute__((ext_vector_type(8)));
typedef __bf16 bf16x4 __attribute__((ext_vector_type(4)));
typedef float  f32x4  __attribute__((ext_vector_type(4)));

#define LN1E4_OVER_32 0.2878231366242558f

__device__ __forceinline__ void gld16(const void* g, void* l) {
    __builtin_amdgcn_global_load_lds((const __attribute__((address_space(1))) void*)g,
                                     (__attribute__((address_space(3))) void*)l,
                                     16, 0, 0);
}

// swizzled offset (elements) in a [rows][64] bf16 tile: row r, logical 8-elem chunk c
__device__ __forceinline__ int swz64(int r, int c) {
    return r * 64 + (((c + r) & 7) << 3);
}

// ---------------- prep: stage-1 RMSNorm (0..2047) + weight transpose (2048..4095)
// ----------------       + RoPE table fill (4096..5119) ----------------
__global__ __launch_bounds__(256) void prep_k(
    const float* __restrict__ x, const float* __restrict__ wln, __bf16* __restrict__ y,
    const float* w0, const float* w1, const float* w2, const float* w3,
    const float* w4, const float* w5, const float* w6, const float* w7,
    const float* __restrict__ gln, float* __restrict__ rmsbuf,
    __bf16* qkvT_t, __bf16* oT_t, __bf16* qkvT_g, __bf16* oT_g,
    const int* __restrict__ pos, float2* __restrict__ rope)
{
    __shared__ float tile[32][33];
    int bid = blockIdx.x;
    if (bid < 2048) {
        if (bid < 32) rmsbuf[bid * 256 + threadIdx.x] = 0.0f;
        int row = bid * 4 + (threadIdx.x >> 6);
        int l = threadIdx.x & 63;
        const float* xr = x + (size_t)row * 512 + l * 8;
        float4 a = *(const float4*)xr;
        float4 b = *(const float4*)(xr + 4);
        float ss = a.x*a.x + a.y*a.y + a.z*a.z + a.w*a.w
                 + b.x*b.x + b.y*b.y + b.z*b.z + b.w*b.w;
        for (int m = 1; m < 64; m <<= 1) ss += __shfl_xor(ss, m);
        float rms = rsqrtf(ss * (1.0f / 512.0f) + 1e-6f);
        float4 wa = *(const float4*)(wln + l * 8);
        float4 wb = *(const float4*)(wln + l * 8 + 4);
        bf16x8 o;
        o[0] = (__bf16)(a.x * rms * wa.x); o[1] = (__bf16)(a.y * rms * wa.y);
        o[2] = (__bf16)(a.z * rms * wa.z); o[3] = (__bf16)(a.w * rms * wa.w);
        o[4] = (__bf16)(b.x * rms * wb.x); o[5] = (__bf16)(b.y * rms * wb.y);
        o[6] = (__bf16)(b.z * rms * wb.z); o[7] = (__bf16)(b.w * rms * wb.w);
        *(bf16x8*)(y + (size_t)row * 512 + l * 8) = o;
        return;
    }
    if (bid >= 4096) {
        int idx = bid - 4096;                  // 0..1023
        int r = threadIdx.x >> 5, i = threadIdx.x & 31;
        int row = idx * 8 + r;                 // 0..8191 over (b,t)
        float p = (float)pos[row];
        float f = __expf((float)i * -LN1E4_OVER_32);
        float s, c;
        __sincosf(p * f, &s, &c);
        rope[(size_t)row * 32 + i] = make_float2(c, s);
        return;
    }
    int bid2 = bid - 2048;
    int mat = bid2 >> 8, rem = bid2 & 255;
    const float* src; __bf16* dst; int rowOff;
    switch (mat) {
        case 0: src=w0; dst=qkvT_t; rowOff=0;    break;
        case 1: src=w1; dst=qkvT_t; rowOff=512;  break;
        case 2: src=w2; dst=qkvT_t; rowOff=1024; break;
        case 3: src=w3; dst=oT_t;   rowOff=0;    break;
        case 4: src=w4; dst=qkvT_g; rowOff=0;    break;
        case 5: src=w5; dst=qkvT_g; rowOff=512;  break;
        case 6: src=w6; dst=qkvT_g; rowOff=1024; break;
        default: src=w7; dst=oT_g;  rowOff=0;    break;
    }
    bool foldG = (mat >= 4 && mat <= 6);
    int n0 = (rem & 15) * 32, k0 = (rem >> 4) * 32;
    int tt = threadIdx.x;
    int kr = tt >> 3, nc = (tt & 7) * 4;
    float4 v = *(const float4*)(src + (size_t)(k0 + kr) * 512 + n0 + nc);
    tile[kr][nc+0] = v.x; tile[kr][nc+1] = v.y; tile[kr][nc+2] = v.z; tile[kr][nc+3] = v.w;
    __syncthreads();
    int nr = tt >> 3, kc = (tt & 7) * 4;
    float g0 = 1.f, g1 = 1.f, g2 = 1.f, g3 = 1.f;
    if (foldG) {
        float4 gv = *(const float4*)(gln + k0 + kc);
        g0 = gv.x; g1 = gv.y; g2 = gv.z; g3 = gv.w;
    }
    bf16x4 o;
    o[0] = (__bf16)(tile[kc+0][nr] * g0); o[1] = (__bf16)(tile[kc+1][nr] * g1);
    o[2] = (__bf16)(tile[kc+2][nr] * g2); o[3] = (__bf16)(tile[kc+3][nr] * g3);
    *(bf16x4*)(dst + (size_t)(rowOff + n0 + nr) * 512 + k0 + kc) = o;
}

// ---------------- 256x256 QKV GEMM, 8 waves, counted-vmcnt depth-2 pipeline ----------------
// mode 0: A already normed (stage 1); RoPE via precomputed table. mode 2: A = raw
// bf16 h2b (t,b order); epilogue scales rows by rsqrt(rmsv[row]/512+eps).
__global__ __launch_bounds__(512) void gemm_ep(
    const __bf16* __restrict__ A, const __bf16* __restrict__ Bt,
    const float2* __restrict__ rope, const float* __restrict__ rmsv,
    __bf16* __restrict__ o0, __bf16* __restrict__ o1, __bf16* __restrict__ o2,
    int mode)
{
    __shared__ __bf16 smem[65536];   // [buf2][As 16384 | Bs 16384] elems = 128 KB
    int tid = threadIdx.x;
    int l = tid & 63, w = tid >> 6;            // 8 waves
    int l16 = l & 15, quad = l >> 4;
    int wm = w >> 2, wn = w & 3;               // 2 (M) x 4 (N)
    int mblk = blockIdx.x * 256, nblk = blockIdx.y * 256;
    f32x4 acc[8][4] = {};

    auto stage = [&](int kt, int bb) {
        int k0 = kt * 64;
        __bf16* As = smem + bb * 32768;
        __bf16* Bs = As + 16384;
        #pragma unroll
        for (int i = 0; i < 4; ++i) {
            int idx = i * 512 + tid;
            int row = idx >> 3, cp = idx & 7;
            int cl = (cp - row) & 7;
            gld16(A + (size_t)(mblk + row) * 512 + k0 + cl * 8, (char*)As + (size_t)idx * 16);
        }
        #pragma unroll
        for (int i = 0; i < 4; ++i) {
            int idx = i * 512 + tid;
            int row = idx >> 3, cp = idx & 7;
            int cl = (cp - row) & 7;
            gld16(Bt + (size_t)(nblk + row) * 512 + k0 + cl * 8, (char*)Bs + (size_t)idx * 16);
        }
    };

    stage(0, 0);
    stage(1, 1);
    asm volatile("s_waitcnt vmcnt(8)" ::: "memory");   // tile 0 landed (per wave)
    __builtin_amdgcn_s_barrier();                      // -> landed for all waves
    __builtin_amdgcn_sched_barrier(0);

    #pragma unroll 1
    for (int t = 0; t < 8; ++t) {
        const __bf16* As = smem + (t & 1) * 32768;
        const __bf16* Bs = As + 16384;
        bf16x8 bF[4][2];
        #pragma unroll
        for (int nt = 0; nt < 4; nt++)
            #pragma unroll
            for (int h = 0; h < 2; h++)
                bF[nt][h] = *(const bf16x8*)(Bs + swz64(wn * 64 + nt * 16 + l16, h * 4 + quad));
        #pragma unroll
        for (int p = 0; p < 4; p++) {
            bf16x8 aF[2][2];
            #pragma unroll
            for (int m2 = 0; m2 < 2; m2++)
                #pragma unroll
                for (int h = 0; h < 2; h++)
                    aF[m2][h] = *(const bf16x8*)(As + swz64(wm * 128 + (p * 2 + m2) * 16 + l16, h * 4 + quad));
            __builtin_amdgcn_s_setprio(1);
            #pragma unroll
            for (int m2 = 0; m2 < 2; m2++)
                #pragma unroll
                for (int nt = 0; nt < 4; nt++)
                    #pragma unroll
                    for (int h = 0; h < 2; h++)
                        acc[p * 2 + m2][nt] = __builtin_amdgcn_mfma_f32_16x16x32_bf16(
                            aF[m2][h], bF[nt][h], acc[p * 2 + m2][nt], 0, 0, 0);
            __builtin_amdgcn_s_setprio(0);
        }
        __builtin_amdgcn_s_barrier();          // all waves done reading buf (t&1)
        if (t < 6) stage(t + 2, t & 1);        // overwrite just-freed buffer
        if (t < 7) {
            if (t < 6) asm volatile("s_waitcnt vmcnt(8)" ::: "memory");  // tile t+1 done
            else       asm volatile("s_waitcnt vmcnt(0)" ::: "memory");  // last tile
            __builtin_amdgcn_s_barrier();
            __builtin_amdgcn_sched_barrier(0);
        }
    }
    __syncthreads();

    int colbase = nblk + wn * 64;
    __bf16* bw = smem + w * 1536;
    int rbrow = l >> 3, rbch = (l & 7) * 8;

    int mat = colbase >> 9;
    int hh  = (colbase & 511) >> 6;
    __bf16* dst = (mat == 0) ? o0 : (mat == 1) ? o1 : o2;
    bool isQ = (mat == 0), isV = (mat == 2);
    if (mode == 0 && !isV) {
        #pragma unroll
        for (int mt = 0; mt < 8; mt++) {
            int grow0 = mblk + wm * 128 + mt * 16;
            int b = grow0 >> 10, t0 = grow0 & 1023;
            #pragma unroll
            for (int r = 0; r < 4; r++) {
                const float2* tp = rope + (size_t)(grow0 + quad * 4 + r) * 32;
                #pragma unroll
                for (int nt = 0; nt < 2; nt++) {
                    int i = nt * 16 + l16;
                    float2 cs = tp[i];
                    float x1 = acc[mt][nt][r], x2 = acc[mt][nt + 2][r];
                    float y1 = x1 * cs.x - x2 * cs.y;
                    float y2 = x2 * cs.x + x1 * cs.y;
                    if (isQ) { y1 *= 0.125f; y2 *= 0.125f; }
                    bw[(quad * 4 + r) * 72 + i]      = (__bf16)y1;
                    bw[(quad * 4 + r) * 72 + i + 32] = (__bf16)y2;
                }
            }
            #pragma unroll
            for (int i = 0; i < 2; ++i) {
                int rr = rbrow + i * 8;
                bf16x8 vv = *(bf16x8*)&bw[rr * 72 + rbch];
                *(bf16x8*)&dst[((size_t)(b * 8 + hh) * 1024 + t0 + rr) * 64 + rbch] = vv;
            }
        }
    } else if (mode == 0) {
        #pragma unroll
        for (int mt = 0; mt < 8; mt++) {
            #pragma unroll
            for (int nt = 0; nt < 4; nt++) {
                bf16x4 o4;
                #pragma unroll
                for (int r = 0; r < 4; r++) o4[r] = (__bf16)acc[mt][nt][r];
                *(bf16x4*)&bw[(nt * 16 + l16) * 24 + quad * 4] = o4;
            }
            int grow0 = mblk + wm * 128 + mt * 16;
            int b = grow0 >> 10, t0 = grow0 & 1023;
            #pragma unroll
            for (int i = 0; i < 2; ++i) {
                int li = i * 64 + l;
                int d = li >> 1, t8 = (li & 1) * 8;
                bf16x8 vv = *(bf16x8*)&bw[d * 24 + t8];
                *(bf16x8*)&dst[((size_t)(b * 8 + hh) * 64 + d) * 1024 + t0 + t8] = vv;
            }
        }
    } else {
        // mode 2: scale rows by rsqrt(sumsq/512+eps), then [t][h][b][d] bounce
        #pragma unroll
        for (int mt = 0; mt < 8; mt++) {
            int grow0 = mblk + wm * 128 + mt * 16;
            f32x4 ss4 = *(const f32x4*)&rmsv[grow0 + quad * 4];
            float rsq[4];
            #pragma unroll
            for (int r = 0; r < 4; r++)
                rsq[r] = rsqrtf(ss4[r] * (1.0f / 512.0f) + 1e-6f) * (isQ ? 0.125f : 1.0f);
            #pragma unroll
            for (int nt = 0; nt < 4; nt++)
                #pragma unroll
                for (int r = 0; r < 4; r++)
                    bw[(quad * 4 + r) * 72 + nt * 16 + l16] = (__bf16)(acc[mt][nt][r] * rsq[r]);
            #pragma unroll
            for (int i = 0; i < 2; ++i) {
                int rr = rbrow + i * 8;
                int grow = grow0 + rr;
                int t = grow >> 3, bq = grow & 7;
                bf16x8 vv = *(bf16x8*)&bw[rr * 72 + rbch];
                *(bf16x8*)&dst[(((size_t)t * 8 + hh) * 8 + bq) * 64 + rbch] = vv;
            }
        }
    }
}

// ---------------- O-projection GEMM: BM=128, BN=128, BK=64, fused residual ----------------
// remap=0 (stage 1): fp32 out rows direct; also writes bf16 h2b in (t,b) order
// and atomically accumulates per-row sumsq into rmsbuf[(t,b)-row].
// remap=1 (stage 2): rows (t,b) -> (b,t), fp32 out only.
__global__ __launch_bounds__(256) void gemm_o(
    const __bf16* __restrict__ A, const __bf16* __restrict__ Bt,
    const float* __restrict__ resid, float* __restrict__ outF,
    __bf16* __restrict__ h2b, float* __restrict__ rmsbuf, int remap)
{
    __shared__ __align__(16) char smemraw[32768];
    __bf16* As = (__bf16*)smemraw;
    __bf16* Bs = (__bf16*)(smemraw + 16384);
    int tid = threadIdx.x;
    int l = tid & 63, w = tid >> 6;
    int l16 = l & 15, quad = l >> 4;
    int wm = w >> 1, wn = w & 1;
    int mblk = blockIdx.x * 128, nblk = blockIdx.y * 128;
    f32x4 acc[4][4] = {};

    for (int k0 = 0; k0 < 512; k0 += 64) {
        __syncthreads();
        #pragma unroll
        for (int i = 0; i < 4; ++i) {
            int idx = i * 256 + tid;
            int row = idx >> 3, cp = idx & 7;
            int cl = (cp - row) & 7;
            gld16(A  + (size_t)(mblk + row) * 512 + k0 + cl * 8, (char*)As + (size_t)idx * 16);
            gld16(Bt + (size_t)(nblk + row) * 512 + k0 + cl * 8, (char*)Bs + (size_t)idx * 16);
        }
        __syncthreads();
        #pragma unroll
        for (int h = 0; h < 2; h++) {
            bf16x8 aF[4], bF[4];
            #pragma unroll
            for (int mt = 0; mt < 4; mt++) aF[mt] = *(bf16x8*)(As + swz64(wm * 64 + mt * 16 + l16, h * 4 + quad));
            #pragma unroll
            for (int nt = 0; nt < 4; nt++) bF[nt] = *(bf16x8*)(Bs + swz64(wn * 64 + nt * 16 + l16, h * 4 + quad));
            #pragma unroll
            for (int mt = 0; mt < 4; mt++)
                #pragma unroll
                for (int nt = 0; nt < 4; nt++)
                    acc[mt][nt] = __builtin_amdgcn_mfma_f32_16x16x32_bf16(aF[mt], bF[nt], acc[mt][nt], 0, 0, 0);
        }
    }
    __syncthreads();

    float* fw = (float*)(smemraw + w * 4352);   // per-wave [16][68] fp32 (17408 B total)
    #pragma unroll
    for (int mt = 0; mt < 4; mt++) {
        int grow0 = mblk + wm * 64 + mt * 16;
        #pragma unroll
        for (int nt = 0; nt < 4; nt++)
            #pragma unroll
            for (int r = 0; r < 4; r++)
                fw[(quad * 4 + r) * 68 + nt * 16 + l16] = acc[mt][nt][r];
        #pragma unroll
        for (int i = 0; i < 4; ++i) {
            int rr = i * 4 + (l >> 4);
            int c4 = (l & 15) * 4;
            f32x4 a4 = *(f32x4*)&fw[rr * 68 + c4];
            int grow = grow0 + rr;
            int orow = remap ? (((grow & 7) << 10) + (grow >> 3)) : grow;
            size_t oi = (size_t)orow * 512 + nblk + wn * 64 + c4;
            f32x4 r4 = *(const f32x4*)&resid[oi];
            r4 += a4;
            *(f32x4*)&outF[oi] = r4;
            if (!remap) {
                int b = grow >> 10, tt2 = grow & 1023;
                int orow2 = tt2 * 8 + b;
                bf16x4 h4;
                h4[0] = (__bf16)r4[0]; h4[1] = (__bf16)r4[1];
                h4[2] = (__bf16)r4[2]; h4[3] = (__bf16)r4[3];
                *(bf16x4*)&h2b[(size_t)orow2 * 512 + nblk + wn * 64 + c4] = h4;
                float s = r4[0]*r4[0] + r4[1]*r4[1] + r4[2]*r4[2] + r4[3]*r4[3];
                s += __shfl_xor(s, 1);
                s += __shfl_xor(s, 2);
                s += __shfl_xor(s, 4);
                s += __shfl_xor(s, 8);
                if ((l & 15) == 0)
                    atomicAdd(&rmsbuf[(grow & 1023) * 8 + (grow >> 10)], s);
            }
        }
    }
}

// ---------------- flash attention (time axis): 128 q-rows/block, no-max softmax ----------------
__global__ __launch_bounds__(512) void flash_t(
    const __bf16* __restrict__ q, const __bf16* __restrict__ k,
    const __bf16* __restrict__ vt, const float* __restrict__ tmask,
    __bf16* __restrict__ ctx)
{
    int bh = blockIdx.x;
    int w = threadIdx.x >> 6, l = threadIdx.x & 63;
    int l16 = l & 15, quad = l >> 4;
    int q0 = blockIdx.y * 128 + w * 16;

    __shared__ __bf16 Ks[64 * 72];
    __shared__ __bf16 Vs[64 * 72];
    __shared__ __bf16 Ps[8][16 * 72];

    bf16x8 aQ0, aQ1;
    {
        const __bf16* qp = q + ((size_t)bh * 1024 + q0 + l16) * 64 + quad * 8;
        aQ0 = *(const bf16x8*)qp;
        aQ1 = *(const bf16x8*)(qp + 32);
    }
    f32x4 o[4] = {};
    float l_acc[4] = {0.0f, 0.0f, 0.0f, 0.0f};

    const float* mrow = tmask + (size_t)bh * 1024 * 1024 + (size_t)(q0 + quad * 4) * 1024 + l16;
    float mc[16];
    #pragma unroll
    for (int r = 0; r < 4; r++)
        #pragma unroll
        for (int nt = 0; nt < 4; nt++)
            mc[r * 4 + nt] = __builtin_nontemporal_load(mrow + (size_t)r * 1024 + nt * 16);

    int c = threadIdx.x;
    int srow = c >> 3, scol = (c & 7) << 3;
    const __bf16* kbase = k  + ((size_t)bh * 1024 + srow) * 64 + scol;
    const __bf16* vbase = vt + ((size_t)bh * 64 + srow) * 1024 + scol;
    bf16x8 kreg = *(const bf16x8*)kbase;
    bf16x8 vreg = *(const bf16x8*)vbase;

    for (int jb = 0; jb < 1024; jb += 64) {
        __syncthreads();
        *(bf16x8*)&Ks[srow * 72 + scol] = kreg;
        *(bf16x8*)&Vs[srow * 72 + scol] = vreg;
        __syncthreads();
        if (jb + 64 < 1024) {
            kreg = *(const bf16x8*)(kbase + (size_t)(jb + 64) * 64);
            vreg = *(const bf16x8*)(vbase + (jb + 64));
        }

        float mn_[16];
        {
            int jb2 = (jb + 64) & 1023;
            const float* mr2 = mrow + jb2;
            #pragma unroll
            for (int r = 0; r < 4; r++)
                #pragma unroll
                for (int nt = 0; nt < 4; nt++)
                    mn_[r * 4 + nt] = __builtin_nontemporal_load(mr2 + (size_t)r * 1024 + nt * 16);
        }

        f32x4 s[4] = {};
        #pragma unroll
        for (int nt = 0; nt < 4; nt++) {
            bf16x8 b0 = *(bf16x8*)&Ks[(nt * 16 + l16) * 72 + quad * 8];
            bf16x8 b1 = *(bf16x8*)&Ks[(nt * 16 + l16) * 72 + 32 + quad * 8];
            s[nt] = __builtin_amdgcn_mfma_f32_16x16x32_bf16(aQ0, b0, s[nt], 0, 0, 0);
            s[nt] = __builtin_amdgcn_mfma_f32_16x16x32_bf16(aQ1, b1, s[nt], 0, 0, 0);
        }
        #pragma unroll
        for (int r = 0; r < 4; r++)
            #pragma unroll
            for (int nt = 0; nt < 4; nt++) {
                float p = __expf(s[nt][r] + mc[r * 4 + nt]);
                s[nt][r] = p;
                l_acc[r] += p;
            }

        __bf16* ps = Ps[w];
        #pragma unroll
        for (int nt = 0; nt < 4; nt++)
            #pragma unroll
            for (int r = 0; r < 4; r++)
                ps[(quad * 4 + r) * 72 + nt * 16 + l16] = (__bf16)s[nt][r];
        bf16x8 aP0 = *(bf16x8*)&ps[l16 * 72 + quad * 8];
        bf16x8 aP1 = *(bf16x8*)&ps[l16 * 72 + 32 + quad * 8];
        #pragma unroll
        for (int dt = 0; dt < 4; dt++) {
            bf16x8 bv0 = *(bf16x8*)&Vs[(dt * 16 + l16) * 72 + quad * 8];
            bf16x8 bv1 = *(bf16x8*)&Vs[(dt * 16 + l16) * 72 + 32 + quad * 8];
            o[dt] = __builtin_amdgcn_mfma_f32_16x16x32_bf16(aP0, bv0, o[dt], 0, 0, 0);
            o[dt] = __builtin_amdgcn_mfma_f32_16x16x32_bf16(aP1, bv1, o[dt], 0, 0, 0);
        }

        #pragma unroll
        for (int i = 0; i < 16; i++) mc[i] = mn_[i];
    }

    float inv_l[4];
    #pragma unroll
    for (int r = 0; r < 4; r++) {
        float rs = l_acc[r];
        rs += __shfl_xor(rs, 1);
        rs += __shfl_xor(rs, 2);
        rs += __shfl_xor(rs, 4);
        rs += __shfl_xor(rs, 8);
        inv_l[r] = 1.0f / rs;
    }

    int b = bh >> 3, h = bh & 7;
    __bf16* ps = Ps[w];
    #pragma unroll
    for (int dt = 0; dt < 4; dt++)
        #pragma unroll
        for (int r = 0; r < 4; r++)
            ps[(quad * 4 + r) * 72 + dt * 16 + l16] = (__bf16)(o[dt][r] * inv_l[r]);
    int rbrow = l >> 3, rbch = (l & 7) * 8;
    #pragma unroll
    for (int i = 0; i < 2; ++i) {
        int rr = rbrow + i * 8;
        bf16x8 vv = *(bf16x8*)&ps[rr * 72 + rbch];
        *(bf16x8*)&ctx[((size_t)b * 1024 + q0 + rr) * 512 + h * 64 + rbch] = vv;
    }
}

// ---------------- group attention (seq len 8) : one thread per (t,h,bq) ----------------
__global__ __launch_bounds__(256) void group_attn(
    const __bf16* __restrict__ qg, const __bf16* __restrict__ kg,
    const __bf16* __restrict__ vg, const float* __restrict__ gmask,
    __bf16* __restrict__ ctxg)
{
    int tid = blockIdx.x * 256 + threadIdx.x;
    int t = tid >> 6, h = (tid >> 3) & 7, bq = tid & 7;
    size_t base = ((size_t)t * 8 + h) * 512;

    float qv[64];
    #pragma unroll
    for (int d0 = 0; d0 < 64; d0 += 8) {
        bf16x8 qq = *(const bf16x8*)&qg[base + (size_t)bq * 64 + d0];
        #pragma unroll
        for (int u = 0; u < 8; u++) qv[d0 + u] = (float)qq[u];
    }
    float s[8];
    #pragma unroll
    for (int j = 0; j < 8; j++) {
        float acc = 0.0f;
        #pragma unroll
        for (int d0 = 0; d0 < 64; d0 += 8) {
            bf16x8 kk = *(const bf16x8*)&kg[base + (size_t)j * 64 + d0];
            #pragma unroll
            for (int u = 0; u < 8; u++) acc += qv[d0 + u] * (float)kk[u];
        }
        s[j] = acc + gmask[(((size_t)t * 8 + h) * 8 + bq) * 8 + j];
    }
    float mx = s[0];
    #pragma unroll
    for (int j = 1; j < 8; j++) mx = fmaxf(mx, s[j]);
    float sum = 0.0f;
    #pragma unroll
    for (int j = 0; j < 8; j++) { s[j] = __expf(s[j] - mx); sum += s[j]; }
    float inv = 1.0f / sum;

    #pragma unroll
    for (int d0 = 0; d0 < 64; d0 += 8) {
        float o8[8] = {};
        #pragma unroll
        for (int j = 0; j < 8; j++) {
            bf16x8 vv = *(const bf16x8*)&vg[base + (size_t)j * 64 + d0];
            float pj = s[j];
            #pragma unroll
            for (int u = 0; u < 8; u++) o8[u] += pj * (float)vv[u];
        }
        bf16x8 ob;
        #pragma unroll
        for (int u = 0; u < 8; u++) ob[u] = (__bf16)(o8[u] * inv);
        *(bf16x8*)&ctxg[((size_t)t * 8 + bq) * 512 + h * 64 + d0] = ob;
    }
}

extern "C" void kernel_launch(void* const* d_in, const int* in_sizes, int n_in,
                              void* d_out, int out_size, void* d_ws, size_t ws_size,
                              hipStream_t stream)
{
    const float* h      = (const float*)d_in[0];
    const int*   pos    = (const int*)  d_in[1];
    const float* t_mask = (const float*)d_in[2];
    const float* g_mask = (const float*)d_in[3];
    const float* ln_t_w = (const float*)d_in[4];
    const float* ln_g_w = (const float*)d_in[5];
    const float* wq_t = (const float*)d_in[6];
    const float* wk_t = (const float*)d_in[7];
    const float* wv_t = (const float*)d_in[8];
    const float* wo_t = (const float*)d_in[9];
    const float* wq_g = (const float*)d_in[10];
    const float* wk_g = (const float*)d_in[11];
    const float* wv_g = (const float*)d_in[12];
    const float* wo_g = (const float*)d_in[13];
    float* out = (float*)d_out;

    char* ws = (char*)d_ws;
    const size_t MB = 1ull << 20;
    __bf16* qkvT_t = (__bf16*)ws;
    __bf16* oT_t   = qkvT_t + 786432;
    __bf16* qkvT_g = qkvT_t + 1048576;
    __bf16* oT_g   = qkvT_t + 1835008;
    __bf16* normed = (__bf16*)(ws + 4 * MB);
    __bf16* qb     = (__bf16*)(ws + 12 * MB);
    __bf16* kb     = (__bf16*)(ws + 20 * MB);
    __bf16* vb     = (__bf16*)(ws + 28 * MB);
    __bf16* ctx    = (__bf16*)(ws + 36 * MB);
    float*  h2     = (float*) (ws + 44 * MB);   // 16 MB, ends at 60 MB
    float*  rmsbuf = (float*) (ws + 60 * MB);   // 32 KB
    __bf16* h2b    = (__bf16*)(ws + 61 * MB);   // 8 MB, ends at 69 MB
    float2* rope   = (float2*)(ws + 70 * MB);   // 2 MB, ends at 72 MB

    // ---- stage 1: norm + weight transpose + rope table fused ----
    prep_k<<<5120, 256, 0, stream>>>(h, ln_t_w, normed,
        wq_t, wk_t, wv_t, wo_t, wq_g, wk_g, wv_g, wo_g,
        ln_g_w, rmsbuf, qkvT_t, oT_t, qkvT_g, oT_g, pos, rope);
    gemm_ep<<<dim3(32, 6), 512, 0, stream>>>(normed, qkvT_t, rope, nullptr, qb, kb, vb, 0);
    flash_t<<<dim3(64, 8), 512, 0, stream>>>(qb, kb, vb, t_mask, ctx);
    gemm_o<<<dim3(64, 4), 256, 0, stream>>>(ctx, oT_t, h, h2, h2b, rmsbuf, 0);

    // ---- stage 2: group attention (norm fused into GEMMs) ----
    gemm_ep<<<dim3(32, 6), 512, 0, stream>>>(h2b, qkvT_g, nullptr, rmsbuf, qb, kb, vb, 2);
    group_attn<<<256, 256, 0, stream>>>(qb, kb, vb, g_mask, ctx);
    gemm_o<<<dim3(64, 4), 256, 0, stream>>>(ctx, oT_g, h2, out, nullptr, nullptr, 1);
}

// Round 3
// 493.637 us; speedup vs baseline: 1.0207x; 1.0207x over previous
//
#include <hip/hip_runtime.h>
#include <hip/hip_bf16.h>
#include <math.h>

// Dual-attention block, bf16 MFMA. R12 = R10 (best, 496.7us) + T5 setprio in
// flash_t MFMA clusters + float4 gmask loads in group_attn. R11's 256x2 tile
// gemm restructure REVERTED (regressed +7us: 1 block/CU at 128KB LDS, 192-block
// grid, 8 K-steps too shallow for the deep pipeline -- regime mismatch).
// ws layout (bytes from d_ws; ws is 1GB):
//   0..4MB    bf16 weights  | 4..12 normed | 12..20 qb | 20..28 kb | 28..36 vb
//   36..44    ctx | 44..60 h2 (fp32) | 60..60.03 rmsbuf | 61..69 h2b
//   70..72    rope table (float2[8192][32])

typedef __bf16 bf16x8 __attribute__((ext_vector_type(8)));
typedef __bf16 bf16x4 __attribute__((ext_vector_type(4)));
typedef float  f32x4  __attribute__((ext_vector_type(4)));

#define LN1E4_OVER_32 0.2878231366242558f

__device__ __forceinline__ void gld16(const void* g, void* l) {
    __builtin_amdgcn_global_load_lds((const __attribute__((address_space(1))) void*)g,
                                     (__attribute__((address_space(3))) void*)l,
                                     16, 0, 0);
}

// swizzled offset (elements) in a [rows][64] bf16 tile: row r, logical 8-elem chunk c
__device__ __forceinline__ int swz64(int r, int c) {
    return r * 64 + (((c + r) & 7) << 3);
}

// ---------------- prep: stage-1 RMSNorm (0..2047) + weight transpose (2048..4095)
// ----------------       + RoPE table fill (4096..5119) ----------------
__global__ __launch_bounds__(256) void prep_k(
    const float* __restrict__ x, const float* __restrict__ wln, __bf16* __restrict__ y,
    const float* w0, const float* w1, const float* w2, const float* w3,
    const float* w4, const float* w5, const float* w6, const float* w7,
    const float* __restrict__ gln, float* __restrict__ rmsbuf,
    __bf16* qkvT_t, __bf16* oT_t, __bf16* qkvT_g, __bf16* oT_g,
    const int* __restrict__ pos, float2* __restrict__ rope)
{
    __shared__ float tile[32][33];
    int bid = blockIdx.x;
    if (bid < 2048) {
        if (bid < 32) rmsbuf[bid * 256 + threadIdx.x] = 0.0f;
        int row = bid * 4 + (threadIdx.x >> 6);
        int l = threadIdx.x & 63;
        const float* xr = x + (size_t)row * 512 + l * 8;
        float4 a = *(const float4*)xr;
        float4 b = *(const float4*)(xr + 4);
        float ss = a.x*a.x + a.y*a.y + a.z*a.z + a.w*a.w
                 + b.x*b.x + b.y*b.y + b.z*b.z + b.w*b.w;
        for (int m = 1; m < 64; m <<= 1) ss += __shfl_xor(ss, m);
        float rms = rsqrtf(ss * (1.0f / 512.0f) + 1e-6f);
        float4 wa = *(const float4*)(wln + l * 8);
        float4 wb = *(const float4*)(wln + l * 8 + 4);
        bf16x8 o;
        o[0] = (__bf16)(a.x * rms * wa.x); o[1] = (__bf16)(a.y * rms * wa.y);
        o[2] = (__bf16)(a.z * rms * wa.z); o[3] = (__bf16)(a.w * rms * wa.w);
        o[4] = (__bf16)(b.x * rms * wb.x); o[5] = (__bf16)(b.y * rms * wb.y);
        o[6] = (__bf16)(b.z * rms * wb.z); o[7] = (__bf16)(b.w * rms * wb.w);
        *(bf16x8*)(y + (size_t)row * 512 + l * 8) = o;
        return;
    }
    if (bid >= 4096) {
        int idx = bid - 4096;                  // 0..1023
        int r = threadIdx.x >> 5, i = threadIdx.x & 31;
        int row = idx * 8 + r;                 // 0..8191 over (b,t)
        float p = (float)pos[row];
        float f = __expf((float)i * -LN1E4_OVER_32);
        float s, c;
        __sincosf(p * f, &s, &c);
        rope[(size_t)row * 32 + i] = make_float2(c, s);
        return;
    }
    int bid2 = bid - 2048;
    int mat = bid2 >> 8, rem = bid2 & 255;
    const float* src; __bf16* dst; int rowOff;
    switch (mat) {
        case 0: src=w0; dst=qkvT_t; rowOff=0;    break;
        case 1: src=w1; dst=qkvT_t; rowOff=512;  break;
        case 2: src=w2; dst=qkvT_t; rowOff=1024; break;
        case 3: src=w3; dst=oT_t;   rowOff=0;    break;
        case 4: src=w4; dst=qkvT_g; rowOff=0;    break;
        case 5: src=w5; dst=qkvT_g; rowOff=512;  break;
        case 6: src=w6; dst=qkvT_g; rowOff=1024; break;
        default: src=w7; dst=oT_g;  rowOff=0;    break;
    }
    bool foldG = (mat >= 4 && mat <= 6);
    int n0 = (rem & 15) * 32, k0 = (rem >> 4) * 32;
    int tt = threadIdx.x;
    int kr = tt >> 3, nc = (tt & 7) * 4;
    float4 v = *(const float4*)(src + (size_t)(k0 + kr) * 512 + n0 + nc);
    tile[kr][nc+0] = v.x; tile[kr][nc+1] = v.y; tile[kr][nc+2] = v.z; tile[kr][nc+3] = v.w;
    __syncthreads();
    int nr = tt >> 3, kc = (tt & 7) * 4;
    float g0 = 1.f, g1 = 1.f, g2 = 1.f, g3 = 1.f;
    if (foldG) {
        float4 gv = *(const float4*)(gln + k0 + kc);
        g0 = gv.x; g1 = gv.y; g2 = gv.z; g3 = gv.w;
    }
    bf16x4 o;
    o[0] = (__bf16)(tile[kc+0][nr] * g0); o[1] = (__bf16)(tile[kc+1][nr] * g1);
    o[2] = (__bf16)(tile[kc+2][nr] * g2); o[3] = (__bf16)(tile[kc+3][nr] * g3);
    *(bf16x4*)(dst + (size_t)(rowOff + n0 + nr) * 512 + k0 + kc) = o;
}

// ---------------- 128x128 QKV GEMM, BK=64, LDS-bounced epilogues ----------------
// mode 0: A already normed (stage 1); RoPE via precomputed table. mode 2: A = raw
// bf16 h2b (t,b order); epilogue scales rows by rsqrt(rmsv[row]/512+eps).
__global__ __launch_bounds__(256) void gemm_ep(
    const __bf16* __restrict__ A, const __bf16* __restrict__ Bt,
    const float2* __restrict__ rope, const float* __restrict__ rmsv,
    __bf16* __restrict__ o0, __bf16* __restrict__ o1, __bf16* __restrict__ o2,
    int mode)
{
    __shared__ __bf16 smem[16384];     // As[128*64] | Bs[128*64] = 32 KB
    __bf16* As = smem;
    __bf16* Bs = smem + 8192;
    int tid = threadIdx.x;
    int l = tid & 63, w = tid >> 6;
    int l16 = l & 15, quad = l >> 4;
    int wm = w >> 1, wn = w & 1;
    int mblk = blockIdx.x * 128, nblk = blockIdx.y * 128;
    f32x4 acc[4][4] = {};

    for (int k0 = 0; k0 < 512; k0 += 64) {
        __syncthreads();
        #pragma unroll
        for (int i = 0; i < 4; ++i) {
            int idx = i * 256 + tid;
            int row = idx >> 3, cp = idx & 7;
            int cl = (cp - row) & 7;
            gld16(A  + (size_t)(mblk + row) * 512 + k0 + cl * 8, (char*)As + (size_t)idx * 16);
            gld16(Bt + (size_t)(nblk + row) * 512 + k0 + cl * 8, (char*)Bs + (size_t)idx * 16);
        }
        __syncthreads();
        #pragma unroll
        for (int h = 0; h < 2; h++) {
            bf16x8 aF[4], bF[4];
            #pragma unroll
            for (int mt = 0; mt < 4; mt++) aF[mt] = *(bf16x8*)(As + swz64(wm * 64 + mt * 16 + l16, h * 4 + quad));
            #pragma unroll
            for (int nt = 0; nt < 4; nt++) bF[nt] = *(bf16x8*)(Bs + swz64(wn * 64 + nt * 16 + l16, h * 4 + quad));
            #pragma unroll
            for (int mt = 0; mt < 4; mt++)
                #pragma unroll
                for (int nt = 0; nt < 4; nt++)
                    acc[mt][nt] = __builtin_amdgcn_mfma_f32_16x16x32_bf16(aF[mt], bF[nt], acc[mt][nt], 0, 0, 0);
        }
    }
    __syncthreads();

    int colbase = nblk + wn * 64;
    __bf16* bw = smem + w * 1536;
    int rbrow = l >> 3, rbch = (l & 7) * 8;

    int mat = colbase >> 9;
    int hh  = (colbase & 511) >> 6;
    __bf16* dst = (mat == 0) ? o0 : (mat == 1) ? o1 : o2;
    bool isQ = (mat == 0), isV = (mat == 2);
    if (mode == 0 && !isV) {
        #pragma unroll
        for (int mt = 0; mt < 4; mt++) {
            int grow0 = mblk + wm * 64 + mt * 16;
            int b = grow0 >> 10, t0 = grow0 & 1023;
            #pragma unroll
            for (int r = 0; r < 4; r++) {
                const float2* tp = rope + (size_t)(grow0 + quad * 4 + r) * 32;
                #pragma unroll
                for (int nt = 0; nt < 2; nt++) {
                    int i = nt * 16 + l16;
                    float2 cs = tp[i];
                    float x1 = acc[mt][nt][r], x2 = acc[mt][nt + 2][r];
                    float y1 = x1 * cs.x - x2 * cs.y;
                    float y2 = x2 * cs.x + x1 * cs.y;
                    if (isQ) { y1 *= 0.125f; y2 *= 0.125f; }
                    bw[(quad * 4 + r) * 72 + i]      = (__bf16)y1;
                    bw[(quad * 4 + r) * 72 + i + 32] = (__bf16)y2;
                }
            }
            #pragma unroll
            for (int i = 0; i < 2; ++i) {
                int rr = rbrow + i * 8;
                bf16x8 vv = *(bf16x8*)&bw[rr * 72 + rbch];
                *(bf16x8*)&dst[((size_t)(b * 8 + hh) * 1024 + t0 + rr) * 64 + rbch] = vv;
            }
        }
    } else if (mode == 0) {
        #pragma unroll
        for (int mt = 0; mt < 4; mt++) {
            #pragma unroll
            for (int nt = 0; nt < 4; nt++) {
                bf16x4 o4;
                #pragma unroll
                for (int r = 0; r < 4; r++) o4[r] = (__bf16)acc[mt][nt][r];
                *(bf16x4*)&bw[(nt * 16 + l16) * 24 + quad * 4] = o4;
            }
            int grow0 = mblk + wm * 64 + mt * 16;
            int b = grow0 >> 10, t0 = grow0 & 1023;
            #pragma unroll
            for (int i = 0; i < 2; ++i) {
                int li = i * 64 + l;
                int d = li >> 1, t8 = (li & 1) * 8;
                bf16x8 vv = *(bf16x8*)&bw[d * 24 + t8];
                *(bf16x8*)&dst[((size_t)(b * 8 + hh) * 64 + d) * 1024 + t0 + t8] = vv;
            }
        }
    } else {
        // mode 2: scale rows by rsqrt(sumsq/512+eps), then [t][h][b][d] bounce
        #pragma unroll
        for (int mt = 0; mt < 4; mt++) {
            int grow0 = mblk + wm * 64 + mt * 16;
            f32x4 ss4 = *(const f32x4*)&rmsv[grow0 + quad * 4];
            float rsq[4];
            #pragma unroll
            for (int r = 0; r < 4; r++)
                rsq[r] = rsqrtf(ss4[r] * (1.0f / 512.0f) + 1e-6f) * (isQ ? 0.125f : 1.0f);
            #pragma unroll
            for (int nt = 0; nt < 4; nt++)
                #pragma unroll
                for (int r = 0; r < 4; r++)
                    bw[(quad * 4 + r) * 72 + nt * 16 + l16] = (__bf16)(acc[mt][nt][r] * rsq[r]);
            #pragma unroll
            for (int i = 0; i < 2; ++i) {
                int rr = rbrow + i * 8;
                int grow = grow0 + rr;
                int t = grow >> 3, bq = grow & 7;
                bf16x8 vv = *(bf16x8*)&bw[rr * 72 + rbch];
                *(bf16x8*)&dst[(((size_t)t * 8 + hh) * 8 + bq) * 64 + rbch] = vv;
            }
        }
    }
}

// ---------------- O-projection GEMM: BM=64, BN=128, BK=64, fused residual ----------------
// remap=0 (stage 1): fp32 out rows direct; also writes bf16 h2b in (t,b) order
// and atomically accumulates per-row sumsq into rmsbuf[(t,b)-row].
// remap=1 (stage 2): rows (t,b) -> (b,t), fp32 out only.
__global__ __launch_bounds__(256) void gemm_o(
    const __bf16* __restrict__ A, const __bf16* __restrict__ Bt,
    const float* __restrict__ resid, float* __restrict__ outF,
    __bf16* __restrict__ h2b, float* __restrict__ rmsbuf, int remap)
{
    __shared__ __align__(16) char smemraw[24576];
    __bf16* As = (__bf16*)smemraw;
    __bf16* Bs = (__bf16*)(smemraw + 8192);
    int tid = threadIdx.x;
    int l = tid & 63, w = tid >> 6;
    int l16 = l & 15, quad = l >> 4;
    int mblk = blockIdx.x * 64, nblk = blockIdx.y * 128;
    f32x4 acc[8] = {};

    for (int k0 = 0; k0 < 512; k0 += 64) {
        __syncthreads();
        #pragma unroll
        for (int i = 0; i < 2; ++i) {
            int idx = i * 256 + tid;
            int row = idx >> 3, cp = idx & 7;
            int cl = (cp - row) & 7;
            gld16(A + (size_t)(mblk + row) * 512 + k0 + cl * 8, (char*)As + (size_t)idx * 16);
        }
        #pragma unroll
        for (int i = 0; i < 4; ++i) {
            int idx = i * 256 + tid;
            int row = idx >> 3, cp = idx & 7;
            int cl = (cp - row) & 7;
            gld16(Bt + (size_t)(nblk + row) * 512 + k0 + cl * 8, (char*)Bs + (size_t)idx * 16);
        }
        __syncthreads();
        #pragma unroll
        for (int h = 0; h < 2; h++) {
            bf16x8 aF = *(bf16x8*)(As + swz64(w * 16 + l16, h * 4 + quad));
            #pragma unroll
            for (int nt = 0; nt < 8; nt++) {
                bf16x8 bF = *(bf16x8*)(Bs + swz64(nt * 16 + l16, h * 4 + quad));
                acc[nt] = __builtin_amdgcn_mfma_f32_16x16x32_bf16(aF, bF, acc[nt], 0, 0, 0);
            }
        }
    }
    __syncthreads();

    float* fw = (float*)(smemraw + w * 4352);   // per-wave [16][68] fp32
    int grow0 = mblk + w * 16;
    float ssq[4] = {0.f, 0.f, 0.f, 0.f};
    #pragma unroll
    for (int nh = 0; nh < 2; nh++) {
        #pragma unroll
        for (int nt = 0; nt < 4; nt++)
            #pragma unroll
            for (int r = 0; r < 4; r++)
                fw[(quad * 4 + r) * 68 + nt * 16 + l16] = acc[nh * 4 + nt][r];
        #pragma unroll
        for (int i = 0; i < 4; ++i) {
            int rr = i * 4 + (l >> 4);
            int c4 = (l & 15) * 4;
            f32x4 a4 = *(f32x4*)&fw[rr * 68 + c4];
            int grow = grow0 + rr;
            int orow = remap ? (((grow & 7) << 10) + (grow >> 3)) : grow;
            size_t oi = (size_t)orow * 512 + nblk + nh * 64 + c4;
            f32x4 r4 = *(const f32x4*)&resid[oi];
            r4 += a4;
            *(f32x4*)&outF[oi] = r4;
            if (!remap) {
                int b = grow >> 10, t = grow & 1023;
                int orow2 = t * 8 + b;
                bf16x4 h4;
                h4[0] = (__bf16)r4[0]; h4[1] = (__bf16)r4[1];
                h4[2] = (__bf16)r4[2]; h4[3] = (__bf16)r4[3];
                *(bf16x4*)&h2b[(size_t)orow2 * 512 + nblk + nh * 64 + c4] = h4;
                ssq[i] += r4[0]*r4[0] + r4[1]*r4[1] + r4[2]*r4[2] + r4[3]*r4[3];
            }
        }
    }
    if (!remap) {
        #pragma unroll
        for (int i = 0; i < 4; ++i) {
            float s = ssq[i];
            s += __shfl_xor(s, 1);
            s += __shfl_xor(s, 2);
            s += __shfl_xor(s, 4);
            s += __shfl_xor(s, 8);
            if ((l & 15) == 0) {
                int grow = grow0 + i * 4 + (l >> 4);
                int orow2 = (grow & 1023) * 8 + (grow >> 10);
                atomicAdd(&rmsbuf[orow2], s);
            }
        }
    }
}

// ---------------- flash attention (time axis): 128 q-rows/block, no-max softmax ----------------
__global__ __launch_bounds__(512) void flash_t(
    const __bf16* __restrict__ q, const __bf16* __restrict__ k,
    const __bf16* __restrict__ vt, const float* __restrict__ tmask,
    __bf16* __restrict__ ctx)
{
    int bh = blockIdx.x;
    int w = threadIdx.x >> 6, l = threadIdx.x & 63;
    int l16 = l & 15, quad = l >> 4;
    int q0 = blockIdx.y * 128 + w * 16;

    __shared__ __bf16 Ks[64 * 72];
    __shared__ __bf16 Vs[64 * 72];
    __shared__ __bf16 Ps[8][16 * 72];

    bf16x8 aQ0, aQ1;
    {
        const __bf16* qp = q + ((size_t)bh * 1024 + q0 + l16) * 64 + quad * 8;
        aQ0 = *(const bf16x8*)qp;
        aQ1 = *(const bf16x8*)(qp + 32);
    }
    f32x4 o[4] = {};
    float l_acc[4] = {0.0f, 0.0f, 0.0f, 0.0f};

    const float* mrow = tmask + (size_t)bh * 1024 * 1024 + (size_t)(q0 + quad * 4) * 1024 + l16;
    float mc[16];
    #pragma unroll
    for (int r = 0; r < 4; r++)
        #pragma unroll
        for (int nt = 0; nt < 4; nt++)
            mc[r * 4 + nt] = __builtin_nontemporal_load(mrow + (size_t)r * 1024 + nt * 16);

    // T14 async-stage: preload first K/V tile into registers
    int c = threadIdx.x;
    int srow = c >> 3, scol = (c & 7) << 3;
    const __bf16* kbase = k  + ((size_t)bh * 1024 + srow) * 64 + scol;
    const __bf16* vbase = vt + ((size_t)bh * 64 + srow) * 1024 + scol;
    bf16x8 kreg = *(const bf16x8*)kbase;
    bf16x8 vreg = *(const bf16x8*)vbase;

    for (int jb = 0; jb < 1024; jb += 64) {
        __syncthreads();
        *(bf16x8*)&Ks[srow * 72 + scol] = kreg;
        *(bf16x8*)&Vs[srow * 72 + scol] = vreg;
        __syncthreads();
        // issue next K/V tile loads early; they land during this tile's MFMA
        if (jb + 64 < 1024) {
            kreg = *(const bf16x8*)(kbase + (size_t)(jb + 64) * 64);
            vreg = *(const bf16x8*)(vbase + (jb + 64));
        }

        float mn_[16];
        {
            int jb2 = (jb + 64) & 1023;
            const float* mr2 = mrow + jb2;
            #pragma unroll
            for (int r = 0; r < 4; r++)
                #pragma unroll
                for (int nt = 0; nt < 4; nt++)
                    mn_[r * 4 + nt] = __builtin_nontemporal_load(mr2 + (size_t)r * 1024 + nt * 16);
        }

        f32x4 s[4] = {};
        __builtin_amdgcn_s_setprio(1);
        #pragma unroll
        for (int nt = 0; nt < 4; nt++) {
            bf16x8 b0 = *(bf16x8*)&Ks[(nt * 16 + l16) * 72 + quad * 8];
            bf16x8 b1 = *(bf16x8*)&Ks[(nt * 16 + l16) * 72 + 32 + quad * 8];
            s[nt] = __builtin_amdgcn_mfma_f32_16x16x32_bf16(aQ0, b0, s[nt], 0, 0, 0);
            s[nt] = __builtin_amdgcn_mfma_f32_16x16x32_bf16(aQ1, b1, s[nt], 0, 0, 0);
        }
        __builtin_amdgcn_s_setprio(0);
        #pragma unroll
        for (int r = 0; r < 4; r++)
            #pragma unroll
            for (int nt = 0; nt < 4; nt++) {
                float p = __expf(s[nt][r] + mc[r * 4 + nt]);
                s[nt][r] = p;
                l_acc[r] += p;
            }

        __bf16* ps = Ps[w];
        #pragma unroll
        for (int nt = 0; nt < 4; nt++)
            #pragma unroll
            for (int r = 0; r < 4; r++)
                ps[(quad * 4 + r) * 72 + nt * 16 + l16] = (__bf16)s[nt][r];
        bf16x8 aP0 = *(bf16x8*)&ps[l16 * 72 + quad * 8];
        bf16x8 aP1 = *(bf16x8*)&ps[l16 * 72 + 32 + quad * 8];
        __builtin_amdgcn_s_setprio(1);
        #pragma unroll
        for (int dt = 0; dt < 4; dt++) {
            bf16x8 bv0 = *(bf16x8*)&Vs[(dt * 16 + l16) * 72 + quad * 8];
            bf16x8 bv1 = *(bf16x8*)&Vs[(dt * 16 + l16) * 72 + 32 + quad * 8];
            o[dt] = __builtin_amdgcn_mfma_f32_16x16x32_bf16(aP0, bv0, o[dt], 0, 0, 0);
            o[dt] = __builtin_amdgcn_mfma_f32_16x16x32_bf16(aP1, bv1, o[dt], 0, 0, 0);
        }
        __builtin_amdgcn_s_setprio(0);

        #pragma unroll
        for (int i = 0; i < 16; i++) mc[i] = mn_[i];
    }

    float inv_l[4];
    #pragma unroll
    for (int r = 0; r < 4; r++) {
        float rs = l_acc[r];
        rs += __shfl_xor(rs, 1);
        rs += __shfl_xor(rs, 2);
        rs += __shfl_xor(rs, 4);
        rs += __shfl_xor(rs, 8);
        inv_l[r] = 1.0f / rs;
    }

    int b = bh >> 3, h = bh & 7;
    __bf16* ps = Ps[w];
    #pragma unroll
    for (int dt = 0; dt < 4; dt++)
        #pragma unroll
        for (int r = 0; r < 4; r++)
            ps[(quad * 4 + r) * 72 + dt * 16 + l16] = (__bf16)(o[dt][r] * inv_l[r]);
    int rbrow = l >> 3, rbch = (l & 7) * 8;
    #pragma unroll
    for (int i = 0; i < 2; ++i) {
        int rr = rbrow + i * 8;
        bf16x8 vv = *(bf16x8*)&ps[rr * 72 + rbch];
        *(bf16x8*)&ctx[((size_t)b * 1024 + q0 + rr) * 512 + h * 64 + rbch] = vv;
    }
}

// ---------------- group attention (seq len 8) : one thread per (t,h,bq) ----------------
__global__ __launch_bounds__(256) void group_attn(
    const __bf16* __restrict__ qg, const __bf16* __restrict__ kg,
    const __bf16* __restrict__ vg, const float* __restrict__ gmask,
    __bf16* __restrict__ ctxg)
{
    int tid = blockIdx.x * 256 + threadIdx.x;
    int t = tid >> 6, h = (tid >> 3) & 7, bq = tid & 7;
    size_t base = ((size_t)t * 8 + h) * 512;

    float qv[64];
    #pragma unroll
    for (int d0 = 0; d0 < 64; d0 += 8) {
        bf16x8 qq = *(const bf16x8*)&qg[base + (size_t)bq * 64 + d0];
        #pragma unroll
        for (int u = 0; u < 8; u++) qv[d0 + u] = (float)qq[u];
    }
    const float* gm = gmask + (((size_t)t * 8 + h) * 8 + bq) * 8;
    float4 g0 = *(const float4*)gm;
    float4 g1 = *(const float4*)(gm + 4);
    const float gmv[8] = {g0.x, g0.y, g0.z, g0.w, g1.x, g1.y, g1.z, g1.w};
    float s[8];
    #pragma unroll
    for (int j = 0; j < 8; j++) {
        float acc = 0.0f;
        #pragma unroll
        for (int d0 = 0; d0 < 64; d0 += 8) {
            bf16x8 kk = *(const bf16x8*)&kg[base + (size_t)j * 64 + d0];
            #pragma unroll
            for (int u = 0; u < 8; u++) acc += qv[d0 + u] * (float)kk[u];
        }
        s[j] = acc + gmv[j];
    }
    float mx = s[0];
    #pragma unroll
    for (int j = 1; j < 8; j++) mx = fmaxf(mx, s[j]);
    float sum = 0.0f;
    #pragma unroll
    for (int j = 0; j < 8; j++) { s[j] = __expf(s[j] - mx); sum += s[j]; }
    float inv = 1.0f / sum;

    #pragma unroll
    for (int d0 = 0; d0 < 64; d0 += 8) {
        float o8[8] = {};
        #pragma unroll
        for (int j = 0; j < 8; j++) {
            bf16x8 vv = *(const bf16x8*)&vg[base + (size_t)j * 64 + d0];
            float pj = s[j];
            #pragma unroll
            for (int u = 0; u < 8; u++) o8[u] += pj * (float)vv[u];
        }
        bf16x8 ob;
        #pragma unroll
        for (int u = 0; u < 8; u++) ob[u] = (__bf16)(o8[u] * inv);
        *(bf16x8*)&ctxg[((size_t)t * 8 + bq) * 512 + h * 64 + d0] = ob;
    }
}

extern "C" void kernel_launch(void* const* d_in, const int* in_sizes, int n_in,
                              void* d_out, int out_size, void* d_ws, size_t ws_size,
                              hipStream_t stream)
{
    const float* h      = (const float*)d_in[0];
    const int*   pos    = (const int*)  d_in[1];
    const float* t_mask = (const float*)d_in[2];
    const float* g_mask = (const float*)d_in[3];
    const float* ln_t_w = (const float*)d_in[4];
    const float* ln_g_w = (const float*)d_in[5];
    const float* wq_t = (const float*)d_in[6];
    const float* wk_t = (const float*)d_in[7];
    const float* wv_t = (const float*)d_in[8];
    const float* wo_t = (const float*)d_in[9];
    const float* wq_g = (const float*)d_in[10];
    const float* wk_g = (const float*)d_in[11];
    const float* wv_g = (const float*)d_in[12];
    const float* wo_g = (const float*)d_in[13];
    float* out = (float*)d_out;

    char* ws = (char*)d_ws;
    const size_t MB = 1ull << 20;
    __bf16* qkvT_t = (__bf16*)ws;
    __bf16* oT_t   = qkvT_t + 786432;
    __bf16* qkvT_g = qkvT_t + 1048576;
    __bf16* oT_g   = qkvT_t + 1835008;
    __bf16* normed = (__bf16*)(ws + 4 * MB);
    __bf16* qb     = (__bf16*)(ws + 12 * MB);
    __bf16* kb     = (__bf16*)(ws + 20 * MB);
    __bf16* vb     = (__bf16*)(ws + 28 * MB);
    __bf16* ctx    = (__bf16*)(ws + 36 * MB);
    float*  h2     = (float*) (ws + 44 * MB);   // 16 MB, ends at 60 MB
    float*  rmsbuf = (float*) (ws + 60 * MB);   // 32 KB
    __bf16* h2b    = (__bf16*)(ws + 61 * MB);   // 8 MB, ends at 69 MB
    float2* rope   = (float2*)(ws + 70 * MB);   // 2 MB, ends at 72 MB

    // ---- stage 1: norm + weight transpose + rope table fused ----
    prep_k<<<5120, 256, 0, stream>>>(h, ln_t_w, normed,
        wq_t, wk_t, wv_t, wo_t, wq_g, wk_g, wv_g, wo_g,
        ln_g_w, rmsbuf, qkvT_t, oT_t, qkvT_g, oT_g, pos, rope);
    gemm_ep<<<dim3(64, 12), 256, 0, stream>>>(normed, qkvT_t, rope, nullptr, qb, kb, vb, 0);
    flash_t<<<dim3(64, 8), 512, 0, stream>>>(qb, kb, vb, t_mask, ctx);
    gemm_o<<<dim3(128, 4), 256, 0, stream>>>(ctx, oT_t, h, h2, h2b, rmsbuf, 0);

    // ---- stage 2: group attention (norm fused into GEMMs) ----
    gemm_ep<<<dim3(64, 12), 256, 0, stream>>>(h2b, qkvT_g, nullptr, rmsbuf, qb, kb, vb, 2);
    group_attn<<<256, 256, 0, stream>>>(qb, kb, vb, g_mask, ctx);
    gemm_o<<<dim3(128, 4), 256, 0, stream>>>(ctx, oT_g, h2, out, nullptr, nullptr, 1);
}